// Round 3
// baseline (481.301 us; speedup 1.0000x reference)
//
#include <hip/hip_runtime.h>
#include <math.h>

#define N_ROWS 65536
#define ZDIM   256
#define KCODES 1024
#define IDX_OFF  (N_ROWS * ZDIM)        // 16777216
#define LOSS_OFF (IDX_OFF + N_ROWS)     // 16842752
#define ZQ_BLOCKS 2048

// ---------------- numpy-pairwise row sum of squares (256 cols) ----------------
__device__ __forceinline__ float np_pw128_sq(const float* __restrict__ p) {
    float r[8];
#pragma unroll
    for (int j = 0; j < 8; ++j) r[j] = __fmul_rn(p[j], p[j]);
    for (int i = 8; i < 128; i += 8) {
#pragma unroll
        for (int j = 0; j < 8; ++j)
            r[j] = __fadd_rn(r[j], __fmul_rn(p[i + j], p[i + j]));
    }
    float a = __fadd_rn(__fadd_rn(r[0], r[1]), __fadd_rn(r[2], r[3]));
    float b = __fadd_rn(__fadd_rn(r[4], r[5]), __fadd_rn(r[6], r[7]));
    return __fadd_rn(a, b);
}

__global__ void rowsq_kernel(const float* __restrict__ x, float* __restrict__ s, int nrows) {
    int r = blockIdx.x * blockDim.x + threadIdx.x;
    if (r >= nrows) return;
    const float* p = x + (size_t)r * ZDIM;
    s[r] = __fadd_rn(np_pw128_sq(p), np_pw128_sq(p + 128));
}

// ---------------- main distance + argmin kernel (v3: 8x16 tile, swizzled LDS) --
// Block 256 thr: tr=tid>>4 (16 row-groups x 8 rows), tc=tid&15 (16 code-groups
// x 16 codes). Block tile: 128 rows x 256 codes (ct loop x4 covers 1024).
// K staged in 8 chunks of 32 dims.
// LDS layouts (all accesses <=2-way bank aliased = free):
//   zt: val(z[row][k]) at  k*128 + (row ^ (4*((k>>2)&7)))          (16 KB)
//   et: val(e[c][k])   at  k*260 + (perm(c) ^ (4*((k>>2)&7)))      (33.3 KB)
//        perm(c) = (c&3) + 4*(c>>4) + 64*((c>>2)&3)
// XORs touch bits 2-4 only -> 4-element b128 blocks stay contiguous & 16B
// aligned, and low-2-bit ordering (k-chain / code order) is preserved, so the
// OpenBLAS-exact sequential-k fmaf accumulation is unchanged.
__global__ __launch_bounds__(256, 2) void argmin_kernel(
    const float* __restrict__ z, const float* __restrict__ e,
    const float* __restrict__ sz, const float* __restrict__ se,
    int* __restrict__ out_idx, float* __restrict__ out_idx_f) {
    __shared__ float zt[32 * 128];
    __shared__ float et[32 * 260];
    __shared__ float sse[KCODES];
    const int tid = threadIdx.x;
    const int tc = tid & 15;
    const int tr = tid >> 4;
    const int br0 = blockIdx.x * 128;

    // stage se once (4 KB)
    {
        float4 v = *(const float4*)(se + tid * 4);
        *(float4*)(sse + tid * 4) = v;
    }

    float szr[8];
#pragma unroll
    for (int r = 0; r < 8; ++r) szr[r] = sz[br0 + tr * 8 + r];

    float bestd[8];
    int   besti[8];
#pragma unroll
    for (int r = 0; r < 8; ++r) { bestd[r] = __builtin_inff(); besti[r] = 0; }

    for (int ct = 0; ct < 4; ++ct) {
        const int c0 = ct * 256;
        float acc[8][16];
#pragma unroll
        for (int r = 0; r < 8; ++r)
#pragma unroll
            for (int c = 0; c < 16; ++c) acc[r][c] = 0.0f;

        for (int kc = 0; kc < 8; ++kc) {
            const int kb = kc * 32;
            __syncthreads();
            // stage z chunk: 128 rows x 32 dims (writes 2-way: row^4q spreads)
#pragma unroll
            for (int it = 0; it < 4; ++it) {
                int flat = it * 256 + tid;
                int row  = flat >> 3;
                int q    = flat & 7;
                float4 v = *(const float4*)(z + (size_t)(br0 + row) * ZDIM + kb + q * 4);
                int dst = row ^ (q << 2);          // h(4q+i) = 4q for i=0..3
                zt[(q * 4 + 0) * 128 + dst] = v.x;
                zt[(q * 4 + 1) * 128 + dst] = v.y;
                zt[(q * 4 + 2) * 128 + dst] = v.z;
                zt[(q * 4 + 3) * 128 + dst] = v.w;
            }
            // stage e chunk: 256 codes x 32 dims
#pragma unroll
            for (int it = 0; it < 8; ++it) {
                int flat = it * 256 + tid;
                int code = flat >> 3;
                int q    = flat & 7;
                float4 v = *(const float4*)(e + (size_t)(c0 + code) * ZDIM + kb + q * 4);
                int pc  = (code & 3) + ((code >> 4) << 2) + (((code >> 2) & 3) << 6);
                int dst = pc ^ (q << 2);
                et[(q * 4 + 0) * 260 + dst] = v.x;
                et[(q * 4 + 1) * 260 + dst] = v.y;
                et[(q * 4 + 2) * 260 + dst] = v.z;
                et[(q * 4 + 3) * 260 + dst] = v.w;
            }
            __syncthreads();
#pragma unroll 1
            for (int g4 = 0; g4 < 8; ++g4) {
                const int gx  = g4 << 2;
                const int zb0 = (tr * 8) ^ gx;
                const int zb1 = zb0 ^ 4;
                const int eb  = (tc ^ g4) << 2;
#pragma unroll
                for (int kk = 0; kk < 4; ++kk) {
                    const int k = g4 * 4 + kk;
                    const float4 za = *(const float4*)&zt[k * 128 + zb0];
                    const float4 zb = *(const float4*)&zt[k * 128 + zb1];
                    const float4 e0 = *(const float4*)&et[k * 260 + eb];
                    const float4 e1 = *(const float4*)&et[k * 260 + eb + 64];
                    const float4 e2 = *(const float4*)&et[k * 260 + eb + 128];
                    const float4 e3 = *(const float4*)&et[k * 260 + eb + 192];
                    float zf[8]  = {za.x, za.y, za.z, za.w, zb.x, zb.y, zb.z, zb.w};
                    float ef[16] = {e0.x, e0.y, e0.z, e0.w, e1.x, e1.y, e1.z, e1.w,
                                    e2.x, e2.y, e2.z, e2.w, e3.x, e3.y, e3.z, e3.w};
#pragma unroll
                    for (int r = 0; r < 8; ++r)
#pragma unroll
                        for (int c = 0; c < 16; ++c)
                            acc[r][c] = fmaf(zf[r], ef[c], acc[r][c]);
                }
            }
        }
        // epilogue: codes ascending (ct asc, j asc); strict < keeps first
#pragma unroll
        for (int j = 0; j < 16; ++j) {
            int code = c0 + tc * 16 + j;
            float sec = sse[code];
#pragma unroll
            for (int r = 0; r < 8; ++r) {
                float t = __fadd_rn(szr[r], sec);
                float d = __fsub_rn(t, 2.0f * acc[r][j]);
                if (d < bestd[r]) { bestd[r] = d; besti[r] = code; }
            }
        }
    }

    // cross-thread reduction: lexicographic (d, idx) min == first-occurrence
    __syncthreads();
    float2* red = (float2*)zt;   // 128*16 float2 = 16 KB = sizeof(zt)
#pragma unroll
    for (int r = 0; r < 8; ++r)
        red[(tr * 8 + r) * 16 + tc] = make_float2(bestd[r], (float)besti[r]);
    __syncthreads();
    if (tid < 128) {
        float bd = __builtin_inff();
        float bi = 0.0f;
        for (int t = 0; t < 16; ++t) {
            float2 v = red[tid * 16 + t];
            if (v.x < bd || (v.x == bd && v.y < bi)) { bd = v.x; bi = v.y; }
        }
        out_idx[br0 + tid]   = (int)bi;
        out_idx_f[br0 + tid] = bi;
    }
}

// ---------------- z_q_st + loss partial (no atomics) ----------------
__global__ __launch_bounds__(256) void zq_loss_kernel(
    const float* __restrict__ z, const float* __restrict__ e,
    const int* __restrict__ idx, float* __restrict__ out,
    double* __restrict__ partial) {
    const int tid = threadIdx.x;
    const int rl  = tid >> 6;
    const int ln  = tid & 63;
    const int row0 = blockIdx.x * 32;

    float acc = 0.0f;
#pragma unroll
    for (int it = 0; it < 8; ++it) {
        int row = row0 + it * 4 + rl;
        int code = idx[row];
        const float4 vz = *(const float4*)(z + (size_t)row  * ZDIM + ln * 4);
        const float4 vq = *(const float4*)(e + (size_t)code * ZDIM + ln * 4);
        float4 o;
        float dx = __fsub_rn(vq.x, vz.x);
        float dy = __fsub_rn(vq.y, vz.y);
        float dz_ = __fsub_rn(vq.z, vz.z);
        float dw = __fsub_rn(vq.w, vz.w);
        o.x = __fadd_rn(vz.x, dx);
        o.y = __fadd_rn(vz.y, dy);
        o.z = __fadd_rn(vz.z, dz_);
        o.w = __fadd_rn(vz.w, dw);
        *(float4*)(out + (size_t)row * ZDIM + ln * 4) = o;
        acc = __fadd_rn(acc, __fmul_rn(dx, dx));
        acc = __fadd_rn(acc, __fmul_rn(dy, dy));
        acc = __fadd_rn(acc, __fmul_rn(dz_, dz_));
        acc = __fadd_rn(acc, __fmul_rn(dw, dw));
    }

    __shared__ double red[256];
    red[tid] = (double)acc;
    __syncthreads();
#pragma unroll
    for (int s = 128; s > 0; s >>= 1) {
        if (tid < s) red[tid] += red[tid + s];
        __syncthreads();
    }
    if (tid == 0) partial[blockIdx.x] = red[0];
}

__global__ __launch_bounds__(256) void loss_final_kernel(
    const double* __restrict__ partial, float* __restrict__ out_loss) {
    const int tid = threadIdx.x;
    double s = 0.0;
    for (int i = tid; i < ZQ_BLOCKS; i += 256) s += partial[i];
    __shared__ double red[256];
    red[tid] = s;
    __syncthreads();
#pragma unroll
    for (int st = 128; st > 0; st >>= 1) {
        if (tid < st) red[tid] += red[tid + st];
        __syncthreads();
    }
    if (tid == 0) {
        double M = red[0] / 16777216.0;
        float m32 = (float)M;
        out_loss[0] = __fadd_rn(m32, __fmul_rn(0.25f, m32));
    }
}

extern "C" void kernel_launch(void* const* d_in, const int* in_sizes, int n_in,
                              void* d_out, int out_size, void* d_ws, size_t ws_size,
                              hipStream_t stream) {
    const float* z = (const float*)d_in[0];
    const float* e = (const float*)d_in[1];
    float* out = (float*)d_out;
    char* ws = (char*)d_ws;

    double* partial = (double*)ws;
    float*  sz   = (float*)(ws + ZQ_BLOCKS * sizeof(double));
    float*  se   = (float*)(ws + ZQ_BLOCKS * sizeof(double) + (size_t)N_ROWS * 4);
    int*    idx  = (int*)  (ws + ZQ_BLOCKS * sizeof(double) + (size_t)N_ROWS * 4 + (size_t)KCODES * 4);

    rowsq_kernel<<<N_ROWS / 256, 256, 0, stream>>>(z, sz, N_ROWS);
    rowsq_kernel<<<KCODES / 256, 256, 0, stream>>>(e, se, KCODES);
    argmin_kernel<<<N_ROWS / 128, 256, 0, stream>>>(z, e, sz, se, idx, out + IDX_OFF);
    zq_loss_kernel<<<ZQ_BLOCKS, 256, 0, stream>>>(z, e, idx, out, partial);
    loss_final_kernel<<<1, 256, 0, stream>>>(partial, out + LOSS_OFF);
}